// Round 10
// baseline (653.218 us; speedup 1.0000x reference)
//
#include <hip/hip_runtime.h>

// ---------------------------------------------------------------------------
// TraceLevelEncoder: 3x GCNConv -> segment-softmax attention pool -> GRU(2,seq=1,h0=0) -> proj
// Round 10: dispatch diet 2 — 19 -> 12 launches.
//   - k_pack: fill + prescale + wt_all + split_all in one launch (independent)
//   - k_tail: softmax_emb + GRU0 gemm + ep + GRU1 gemm + ep + proj in ONE
//     256-block kernel with device-scope grid barriers (atomic + threadfence;
//     256 blocks always co-resident: 36KB LDS -> >=2 blocks/CU capacity).
// Gather / GEMM cores bit-identical to R9.
// ---------------------------------------------------------------------------

#define N_GRAPHS 256
#define GRU_H 256
#define SCAN_CHUNK 2048   // 256 threads x 8 elements

typedef __attribute__((ext_vector_type(8))) short short8;   // 8 bf16 (4 VGPRs)
typedef __attribute__((ext_vector_type(4))) float floatx4;  // 4 fp32 acc

typedef unsigned short ushort_t;
typedef unsigned int uint_t;

__device__ __forceinline__ float bflo(uint_t u) { return __uint_as_float(u << 16); }
__device__ __forceinline__ float bfhi(uint_t u) { return __uint_as_float(u & 0xffff0000u); }
__device__ __forceinline__ uint_t f2bf(float f) {           // RNE
    uint_t u = __float_as_uint(f);
    return (u + 0x7fffu + ((u >> 16) & 1u)) >> 16;
}
__device__ __forceinline__ uint_t pack2(float a, float b) {
    return f2bf(a) | (f2bf(b) << 16);
}

// ---- CSR build ------------------------------------------------------------

__global__ void k_hist(const int* __restrict__ dst, int* __restrict__ counts, int E) {
    int e = blockIdx.x * blockDim.x + threadIdx.x;
    if (e < E) atomicAdd(&counts[dst[e]], 1);
}

__global__ __launch_bounds__(256) void k_scan1(const int* __restrict__ counts,
                                               int* __restrict__ rowptr,
                                               int* __restrict__ bsums,
                                               float* __restrict__ dinv, int n) {
    int b = blockIdx.x, t = threadIdx.x;
    int base = b * SCAN_CHUNK + t * 8;
    int v[8];
    int s = 0;
#pragma unroll
    for (int j = 0; j < 8; ++j) {
        int i = base + j;
        int c = (i < n) ? counts[i] : 0;
        v[j] = s;            // exclusive within thread
        s += c;
        if (i < n) dinv[i] = rsqrtf((float)(c + 1));  // +1 self loop
    }
    __shared__ int sd[256];
    sd[t] = s;
    __syncthreads();
    for (int off = 1; off < 256; off <<= 1) {
        int tmp = (t >= off) ? sd[t - off] : 0;
        __syncthreads();
        sd[t] += tmp;
        __syncthreads();
    }
    int texcl = sd[t] - s;
    if (t == 255) bsums[b] = sd[255];
#pragma unroll
    for (int j = 0; j < 8; ++j) {
        int i = base + j;
        if (i < n) rowptr[i] = texcl + v[j];
    }
}

// scan3 (scan2 folded): each block derives its own offset from bsums
__global__ __launch_bounds__(256) void k_scan3(int* __restrict__ rowptr,
                                               int* __restrict__ cursor,
                                               const int* __restrict__ bsums,
                                               int n, int nb) {
    int b = blockIdx.x, t = threadIdx.x;
    __shared__ int s_off;
    if (t == 0) {
        int off = 0, tot = 0;
        for (int i = 0; i < nb; ++i) {
            int v = bsums[i];
            if (i < b) off += v;
            tot += v;
        }
        s_off = off;
        if (b == 0) rowptr[n] = tot;
    }
    __syncthreads();
    int off = s_off;
    int base = b * SCAN_CHUNK + t * 8;
#pragma unroll
    for (int j = 0; j < 8; ++j) {
        int i = base + j;
        if (i < n) { int r = rowptr[i] + off; rowptr[i] = r; cursor[i] = r; }
    }
}

// ---- packed independent kernels: fill | prescale | wt_all | split_all -----

__global__ __launch_bounds__(256) void k_pack(
    // fill
    const int* __restrict__ src, const int* __restrict__ dst,
    int* __restrict__ cursor, int* __restrict__ col, int E,
    // prescale
    const float4* __restrict__ x, const float* __restrict__ dinv,
    uint4* __restrict__ xs, int N,
    // wt_all
    const float* __restrict__ w0, const float* __restrict__ w1,
    const float* __restrict__ w2, ushort_t* __restrict__ wt0,
    ushort_t* __restrict__ wt1, ushort_t* __restrict__ wt2,
    // split_all
    const float* __restrict__ wih0, const float* __restrict__ wih1,
    const float* __restrict__ pw,
    ushort_t* __restrict__ sh0, ushort_t* __restrict__ sl0,
    ushort_t* __restrict__ sh1, ushort_t* __restrict__ sl1,
    ushort_t* __restrict__ sh2, ushort_t* __restrict__ sl2,
    int nf, int np, int nw) {
    int b = blockIdx.x, t = threadIdx.x;
    if (b < nf) {
        int e = b * 256 + t;
        if (e < E) {
            int pos = atomicAdd(&cursor[dst[e]], 1);
            col[pos] = src[e];
        }
    } else if (b < nf + np) {
        int idx = (b - nf) * 256 + t;   // chunk of 8 over N*64
        int n = idx >> 3;
        if (n < N) {
            float dn = dinv[n];
            float4 v0 = x[idx * 2], v1 = x[idx * 2 + 1];
            uint4 o;
            o.x = pack2(v0.x * dn, v0.y * dn);
            o.y = pack2(v0.z * dn, v0.w * dn);
            o.z = pack2(v1.x * dn, v1.y * dn);
            o.w = pack2(v1.z * dn, v1.w * dn);
            xs[idx] = o;
        }
    } else if (b < nf + np + nw) {
        int idx = (b - nf - np) * 256 + t;
        if (idx < 8192) {
            int k = idx >> 7, n = idx & 127;
            wt0[(size_t)n * 64 + k] = (ushort_t)f2bf(w0[idx]);
        } else if (idx < 40960) {
            int i = idx - 8192;
            int k = i >> 8, n = i & 255;
            wt1[(size_t)n * 128 + k] = (ushort_t)f2bf(w1[i]);
        } else if (idx < 172032) {
            int i = idx - 40960;
            int k = i >> 9, n = i & 511;
            wt2[(size_t)n * 256 + k] = (ushort_t)f2bf(w2[i]);
        }
    } else {
        int idx = (b - nf - np - nw) * 256 + t;
        const float* s; ushort_t* H; ushort_t* L; int i;
        if (idx < 393216)      { s = wih0; H = sh0; L = sl0; i = idx; }
        else if (idx < 589824) { s = wih1; H = sh1; L = sl1; i = idx - 393216; }
        else if (idx < 720896) { s = pw;   H = sh2; L = sl2; i = idx - 589824; }
        else return;
        float v = s[i];
        uint_t h = f2bf(v);
        H[i] = (ushort_t)h;
        L[i] = (ushort_t)f2bf(v - __uint_as_float(h << 16));
    }
}

// ---- Edge aggregation (gather over CSR), bf16, fp32 accum, 8x unrolled ----

__device__ __forceinline__ void acc8(float& a0, float& a1, float& a2, float& a3,
                                     float& a4, float& a5, float& a6, float& a7,
                                     const uint4& v) {
    a0 += bflo(v.x); a1 += bfhi(v.x); a2 += bflo(v.y); a3 += bfhi(v.y);
    a4 += bflo(v.z); a5 += bfhi(v.z); a6 += bflo(v.w); a7 += bfhi(v.w);
}

__global__ void k_gather_bf16(const uint4* __restrict__ xs, const int* __restrict__ rp,
                              const int* __restrict__ col, const float* __restrict__ dinv,
                              uint4* __restrict__ agg, int N, int shift /*log2(D/8)*/) {
    int idx = blockIdx.x * blockDim.x + threadIdx.x;
    int n = idx >> shift;
    if (n >= N) return;
    int c = idx & ((1 << shift) - 1);
    int C8 = 1 << shift;
    int a = rp[n], b = rp[n + 1];
    uint4 u = xs[(size_t)n * C8 + c];   // self loop (pre-scaled by dinv[n])
    float a0 = bflo(u.x), a1 = bfhi(u.x), a2 = bflo(u.y), a3 = bfhi(u.y);
    float a4 = bflo(u.z), a5 = bfhi(u.z), a6 = bflo(u.w), a7 = bfhi(u.w);
    int k = a;
    for (; k + 8 <= b; k += 8) {
        int ci[8];
#pragma unroll
        for (int j = 0; j < 8; ++j) ci[j] = col[k + j];
        uint4 v[8];
#pragma unroll
        for (int j = 0; j < 8; ++j) v[j] = xs[(size_t)ci[j] * C8 + c];
#pragma unroll
        for (int j = 0; j < 8; ++j)
            acc8(a0, a1, a2, a3, a4, a5, a6, a7, v[j]);
    }
    for (; k + 4 <= b; k += 4) {
        int ci[4];
#pragma unroll
        for (int j = 0; j < 4; ++j) ci[j] = col[k + j];
        uint4 v[4];
#pragma unroll
        for (int j = 0; j < 4; ++j) v[j] = xs[(size_t)ci[j] * C8 + c];
#pragma unroll
        for (int j = 0; j < 4; ++j)
            acc8(a0, a1, a2, a3, a4, a5, a6, a7, v[j]);
    }
    for (; k < b; ++k) {
        uint4 v = xs[(size_t)col[k] * C8 + c];
        acc8(a0, a1, a2, a3, a4, a5, a6, a7, v);
    }
    float dn = dinv[n];
    uint4 o;
    o.x = pack2(a0 * dn, a1 * dn);
    o.y = pack2(a2 * dn, a3 * dn);
    o.z = pack2(a4 * dn, a5 * dn);
    o.w = pack2(a6 * dn, a7 * dn);
    agg[idx] = o;
}

// ---- MFMA bf16 GEMM (GCN layers): C = postproc(A @ Wt^T + bias) -----------
// 64x64 block tile, BK=64, 4 waves 2x2, each wave 32x32 via 2x2 MFMAs.
// Optional fused gate: gateArr[row] += dot(relu'd row-slice, gate_w-slice).

__global__ __launch_bounds__(256) void k_gemm_mfma(
    const ushort_t* __restrict__ A, const ushort_t* __restrict__ Wt,
    const float* __restrict__ bias, const float* __restrict__ dinv,
    ushort_t* __restrict__ C, int M, int K, int Nout, int scale_out,
    const float* __restrict__ gate_w, float* __restrict__ gateArr) {
    __shared__ ushort_t As[64 * 72];   // stride 72 bf16 (144B rows, 16B-aligned)
    __shared__ ushort_t Bs[64 * 72];
    int tid = threadIdx.x;
    int wave = tid >> 6, lane = tid & 63;
    int quad = lane >> 4, lr = lane & 15;
    int wm = (wave & 1) * 32, wn = (wave >> 1) * 32;
    int bm = blockIdx.x * 64, bn = blockIdx.y * 64;

    floatx4 zero = {0.f, 0.f, 0.f, 0.f};
    floatx4 acc00 = zero, acc01 = zero, acc10 = zero, acc11 = zero;

    int r0 = tid >> 3,         ko0 = (tid & 7) * 8;
    int r1 = (tid + 256) >> 3, ko1 = ((tid + 256) & 7) * 8;

    for (int k0 = 0; k0 < K; k0 += 64) {
        int ar0 = min(bm + r0, M - 1);
        int ar1 = min(bm + r1, M - 1);
        uint4 av0 = *(const uint4*)(A + (size_t)ar0 * K + k0 + ko0);
        uint4 av1 = *(const uint4*)(A + (size_t)ar1 * K + k0 + ko1);
        uint4 bv0 = *(const uint4*)(Wt + (size_t)(bn + r0) * K + k0 + ko0);
        uint4 bv1 = *(const uint4*)(Wt + (size_t)(bn + r1) * K + k0 + ko1);
        __syncthreads();   // prev iter LDS reads done
        *(uint4*)&As[r0 * 72 + ko0] = av0;
        *(uint4*)&As[r1 * 72 + ko1] = av1;
        *(uint4*)&Bs[r0 * 72 + ko0] = bv0;
        *(uint4*)&Bs[r1 * 72 + ko1] = bv1;
        __syncthreads();
#pragma unroll
        for (int ks = 0; ks < 2; ++ks) {
            short8 af0 = *(short8*)&As[(wm + lr) * 72 + ks * 32 + quad * 8];
            short8 af1 = *(short8*)&As[(wm + 16 + lr) * 72 + ks * 32 + quad * 8];
            short8 bf0 = *(short8*)&Bs[(wn + lr) * 72 + ks * 32 + quad * 8];
            short8 bf1 = *(short8*)&Bs[(wn + 16 + lr) * 72 + ks * 32 + quad * 8];
            acc00 = __builtin_amdgcn_mfma_f32_16x16x32_bf16(af0, bf0, acc00, 0, 0, 0);
            acc01 = __builtin_amdgcn_mfma_f32_16x16x32_bf16(af0, bf1, acc01, 0, 0, 0);
            acc10 = __builtin_amdgcn_mfma_f32_16x16x32_bf16(af1, bf0, acc10, 0, 0, 0);
            acc11 = __builtin_amdgcn_mfma_f32_16x16x32_bf16(af1, bf1, acc11, 0, 0, 0);
        }
    }

    // epilogue: C/D layout col=lane&15, row=quad*4+r (m89-verified)
    float gwv[2] = {0.f, 0.f};
    if (gate_w) {
        gwv[0] = gate_w[bn + wn + lr];
        gwv[1] = gate_w[bn + wn + 16 + lr];
    }
    float pg[2][4] = {};
#pragma unroll
    for (int mi = 0; mi < 2; ++mi) {
#pragma unroll
        for (int ni = 0; ni < 2; ++ni) {
            floatx4 acc = (mi == 0) ? (ni == 0 ? acc00 : acc01)
                                    : (ni == 0 ? acc10 : acc11);
            int col = bn + wn + ni * 16 + lr;
            float bcol = bias[col];
#pragma unroll
            for (int r = 0; r < 4; ++r) {
                int row = bm + wm + mi * 16 + quad * 4 + r;
                if (row < M) {
                    float v = acc[r] + bcol;
                    v = fmaxf(v, 0.0f);
                    if (gate_w) pg[mi][r] += v * gwv[ni];
                    if (scale_out) v *= dinv[row];
                    C[(size_t)row * Nout + col] = (ushort_t)f2bf(v);
                }
            }
        }
    }
    if (gate_w) {
#pragma unroll
        for (int mi = 0; mi < 2; ++mi) {
#pragma unroll
            for (int r = 0; r < 4; ++r) {
                float p = pg[mi][r];
                p += __shfl_down(p, 8, 16);
                p += __shfl_down(p, 4, 16);
                p += __shfl_down(p, 2, 16);
                p += __shfl_down(p, 1, 16);
                if (lr == 0) {
                    int row = bm + wm + mi * 16 + quad * 4 + r;
                    if (row < M) atomicAdd(&gateArr[row], p);
                }
            }
        }
    }
}

// ---- split-precision MFMA GEMM body (device fn, LDS from caller) ----------

__device__ __forceinline__ void gemm3_body(
    char* smem,
    const ushort_t* __restrict__ Ahi, const ushort_t* __restrict__ Alo,
    const ushort_t* __restrict__ Whi, const ushort_t* __restrict__ Wlo,
    const float* __restrict__ bias, float* __restrict__ C,
    int M, int K, int Nout, int bm, int bn, int tid) {
    ushort_t* AsH = (ushort_t*)smem;
    ushort_t* AsL = AsH + 64 * 72;
    ushort_t* BsH = AsL + 64 * 72;
    ushort_t* BsL = BsH + 64 * 72;
    int wave = tid >> 6, lane = tid & 63;
    int quad = lane >> 4, lr = lane & 15;
    int wm = (wave & 1) * 32, wn = (wave >> 1) * 32;

    floatx4 zero = {0.f, 0.f, 0.f, 0.f};
    floatx4 acc00 = zero, acc01 = zero, acc10 = zero, acc11 = zero;

    int r0 = tid >> 3,         ko0 = (tid & 7) * 8;
    int r1 = (tid + 256) >> 3, ko1 = ((tid + 256) & 7) * 8;

    for (int k0 = 0; k0 < K; k0 += 64) {
        int ar0 = min(bm + r0, M - 1);
        int ar1 = min(bm + r1, M - 1);
        size_t a0o = (size_t)ar0 * K + k0 + ko0, a1o = (size_t)ar1 * K + k0 + ko1;
        size_t b0o = (size_t)(bn + r0) * K + k0 + ko0, b1o = (size_t)(bn + r1) * K + k0 + ko1;
        uint4 ah0 = *(const uint4*)(Ahi + a0o), ah1 = *(const uint4*)(Ahi + a1o);
        uint4 al0 = *(const uint4*)(Alo + a0o), al1 = *(const uint4*)(Alo + a1o);
        uint4 bh0 = *(const uint4*)(Whi + b0o), bh1 = *(const uint4*)(Whi + b1o);
        uint4 bl0 = *(const uint4*)(Wlo + b0o), bl1 = *(const uint4*)(Wlo + b1o);
        __syncthreads();
        *(uint4*)&AsH[r0 * 72 + ko0] = ah0; *(uint4*)&AsH[r1 * 72 + ko1] = ah1;
        *(uint4*)&AsL[r0 * 72 + ko0] = al0; *(uint4*)&AsL[r1 * 72 + ko1] = al1;
        *(uint4*)&BsH[r0 * 72 + ko0] = bh0; *(uint4*)&BsH[r1 * 72 + ko1] = bh1;
        *(uint4*)&BsL[r0 * 72 + ko0] = bl0; *(uint4*)&BsL[r1 * 72 + ko1] = bl1;
        __syncthreads();
#pragma unroll
        for (int ks = 0; ks < 2; ++ks) {
            int a0i = (wm + lr) * 72 + ks * 32 + quad * 8;
            int a1i = (wm + 16 + lr) * 72 + ks * 32 + quad * 8;
            int b0i = (wn + lr) * 72 + ks * 32 + quad * 8;
            int b1i = (wn + 16 + lr) * 72 + ks * 32 + quad * 8;
            short8 afh0 = *(short8*)&AsH[a0i], afh1 = *(short8*)&AsH[a1i];
            short8 afl0 = *(short8*)&AsL[a0i], afl1 = *(short8*)&AsL[a1i];
            short8 bfh0 = *(short8*)&BsH[b0i], bfh1 = *(short8*)&BsH[b1i];
            short8 bfl0 = *(short8*)&BsL[b0i], bfl1 = *(short8*)&BsL[b1i];
            acc00 = __builtin_amdgcn_mfma_f32_16x16x32_bf16(afh0, bfh0, acc00, 0, 0, 0);
            acc00 = __builtin_amdgcn_mfma_f32_16x16x32_bf16(afh0, bfl0, acc00, 0, 0, 0);
            acc00 = __builtin_amdgcn_mfma_f32_16x16x32_bf16(afl0, bfh0, acc00, 0, 0, 0);
            acc01 = __builtin_amdgcn_mfma_f32_16x16x32_bf16(afh0, bfh1, acc01, 0, 0, 0);
            acc01 = __builtin_amdgcn_mfma_f32_16x16x32_bf16(afh0, bfl1, acc01, 0, 0, 0);
            acc01 = __builtin_amdgcn_mfma_f32_16x16x32_bf16(afl0, bfh1, acc01, 0, 0, 0);
            acc10 = __builtin_amdgcn_mfma_f32_16x16x32_bf16(afh1, bfh0, acc10, 0, 0, 0);
            acc10 = __builtin_amdgcn_mfma_f32_16x16x32_bf16(afh1, bfl0, acc10, 0, 0, 0);
            acc10 = __builtin_amdgcn_mfma_f32_16x16x32_bf16(afl1, bfh0, acc10, 0, 0, 0);
            acc11 = __builtin_amdgcn_mfma_f32_16x16x32_bf16(afh1, bfh1, acc11, 0, 0, 0);
            acc11 = __builtin_amdgcn_mfma_f32_16x16x32_bf16(afh1, bfl1, acc11, 0, 0, 0);
            acc11 = __builtin_amdgcn_mfma_f32_16x16x32_bf16(afl1, bfh1, acc11, 0, 0, 0);
        }
    }

#pragma unroll
    for (int mi = 0; mi < 2; ++mi) {
#pragma unroll
        for (int ni = 0; ni < 2; ++ni) {
            floatx4 acc = (mi == 0) ? (ni == 0 ? acc00 : acc01)
                                    : (ni == 0 ? acc10 : acc11);
            int col = bn + wn + ni * 16 + lr;
            float bcol = bias ? bias[col] : 0.0f;
#pragma unroll
            for (int r = 0; r < 4; ++r) {
                int row = bm + wm + mi * 16 + quad * 4 + r;
                if (row < M)
                    C[(size_t)row * Nout + col] = acc[r] + bcol;
            }
        }
    }
}

// ---- GRU gate epilogue body (h=0: gh = bhh exactly, h' = (1-z)*n) ---------

__device__ __forceinline__ void gru_ep_body(int idx, const float* __restrict__ gi,
                                            const float* __restrict__ bih,
                                            const float* __restrict__ bhh,
                                            ushort_t* __restrict__ hhi,
                                            ushort_t* __restrict__ hlo) {
    int g = idx >> 8, j = idx & 255;
    const float* row = gi + (size_t)g * 768;
    float ir = row[j]       + bih[j]       + bhh[j];
    float iz = row[j + 256] + bih[j + 256] + bhh[j + 256];
    float in = row[j + 512] + bih[j + 512];
    float r = 1.0f / (1.0f + expf(-ir));
    float z = 1.0f / (1.0f + expf(-iz));
    float nn = tanhf(in + r * bhh[j + 512]);
    float h = (1.0f - z) * nn;
    uint_t hi = f2bf(h);
    hhi[idx] = (ushort_t)hi;
    hlo[idx] = (ushort_t)f2bf(h - __uint_as_float(hi << 16));
}

// ---- device-scope grid barrier (256 blocks, all co-resident) --------------

__device__ __forceinline__ void gridbar(int* bar) {
    __threadfence();          // release this block's writes device-wide
    __syncthreads();
    if (threadIdx.x == 0) {
        atomicAdd(bar, 1);
        while (atomicAdd(bar, 0) < N_GRAPHS) {}
    }
    __syncthreads();
    __threadfence();          // acquire: invalidate stale cached lines
}

// ---- fused tail: softmax_emb -> GRU0 -> GRU1 -> proj (one launch) ---------

__global__ __launch_bounds__(256) void k_tail(
    const uint_t* __restrict__ x /*bf16 pairs*/, const float* __restrict__ gate,
    const int* __restrict__ batch, int N,
    const ushort_t* __restrict__ ih0H, const ushort_t* __restrict__ ih0L,
    const ushort_t* __restrict__ ih1H, const ushort_t* __restrict__ ih1L,
    const ushort_t* __restrict__ pwH,  const ushort_t* __restrict__ pwL,
    const float* __restrict__ bih0, const float* __restrict__ bhh0,
    const float* __restrict__ bih1, const float* __restrict__ bhh1,
    const float* __restrict__ pb,
    ushort_t* __restrict__ embH, ushort_t* __restrict__ embL,
    ushort_t* __restrict__ h1H, ushort_t* __restrict__ h1L,
    ushort_t* __restrict__ h2H, ushort_t* __restrict__ h2L,
    float* __restrict__ gi, float* __restrict__ out, int* __restrict__ bars) {
    __shared__ char smem[4 * 64 * 72 * 2];   // 36 KB, reused per stage
    int b = blockIdx.x, tid = threadIdx.x;

    // ---- stage 1: segment softmax + weighted emb for graph b ----
    {
        int g = b;
        int s, e;
        {
            int lo = 0, hi = N;
            while (lo < hi) { int mid = (lo + hi) >> 1; if (batch[mid] < g) lo = mid + 1; else hi = mid; }
            s = lo;
            lo = s; hi = N;
            while (lo < hi) { int mid = (lo + hi) >> 1; if (batch[mid] < g + 1) lo = mid + 1; else hi = mid; }
            e = lo;
        }
        float* red = (float*)smem;
        float* sal = red + 256;
        float m = -INFINITY;
        for (int i = s + tid; i < e; i += 256) m = fmaxf(m, gate[i]);
        red[tid] = m; __syncthreads();
        for (int off = 128; off > 0; off >>= 1) {
            if (tid < off) red[tid] = fmaxf(red[tid], red[tid + off]);
            __syncthreads();
        }
        m = red[0]; __syncthreads();
        float ssum = 0.f;
        for (int i = s + tid; i < e; i += 256) ssum += expf(gate[i] - m);
        red[tid] = ssum; __syncthreads();
        for (int off = 128; off > 0; off >>= 1) {
            if (tid < off) red[tid] += red[tid + off];
            __syncthreads();
        }
        float denom = red[0];
        float inv = (denom > 0.f) ? 1.0f / denom : 0.0f;
        float acc0 = 0.f, acc1 = 0.f;
        for (int base = s; base < e; base += 256) {
            int i = base + tid;
            __syncthreads();
            sal[tid] = (i < e) ? expf(gate[i] - m) * inv : 0.0f;
            __syncthreads();
            int cnt = min(256, e - base);
            for (int k = 0; k < cnt; ++k) {
                float a = sal[k];
                uint_t u = x[(size_t)(base + k) * 256 + tid];
                acc0 += a * bflo(u);
                acc1 += a * bfhi(u);
            }
        }
        int i0 = g * 512 + tid * 2;
        uint_t hh0 = f2bf(acc0);
        uint_t hh1 = f2bf(acc1);
        embH[i0]     = (ushort_t)hh0;
        embH[i0 + 1] = (ushort_t)hh1;
        embL[i0]     = (ushort_t)f2bf(acc0 - __uint_as_float(hh0 << 16));
        embL[i0 + 1] = (ushort_t)f2bf(acc1 - __uint_as_float(hh1 << 16));
    }
    gridbar(&bars[0]);
    // ---- stage 2: gi = emb @ wih0^T  (M=256,K=512,N=768; 4x12=48 tiles) ----
    if (b < 48)
        gemm3_body(smem, embH, embL, ih0H, ih0L, nullptr, gi,
                   256, 512, 768, (b & 3) * 64, (b >> 2) * 64, tid);
    gridbar(&bars[1]);
    // ---- stage 3: GRU0 epilogue ----
    gru_ep_body(b * 256 + tid, gi, bih0, bhh0, h1H, h1L);
    gridbar(&bars[2]);
    // ---- stage 4: gi = h1 @ wih1^T  (M=256,K=256,N=768; 48 tiles) ----
    if (b < 48)
        gemm3_body(smem, h1H, h1L, ih1H, ih1L, nullptr, gi,
                   256, 256, 768, (b & 3) * 64, (b >> 2) * 64, tid);
    gridbar(&bars[3]);
    // ---- stage 5: GRU1 epilogue ----
    gru_ep_body(b * 256 + tid, gi, bih1, bhh1, h2H, h2L);
    gridbar(&bars[4]);
    // ---- stage 6: out = h2 @ pw^T + pb  (M=256,K=256,N=512; 32 tiles) ----
    if (b < 32)
        gemm3_body(smem, h2H, h2L, pwH, pwL, pb, out,
                   256, 256, 512, (b & 3) * 64, (b >> 2) * 64, tid);
}

// ---------------------------------------------------------------------------

extern "C" void kernel_launch(void* const* d_in, const int* in_sizes, int n_in,
                              void* d_out, int out_size, void* d_ws, size_t ws_size,
                              hipStream_t stream) {
    const float* x       = (const float*)d_in[0];
    const int*   ei      = (const int*)d_in[1];
    const int*   batch   = (const int*)d_in[2];
    const float* w0      = (const float*)d_in[3];
    const float* b0      = (const float*)d_in[4];
    const float* w1      = (const float*)d_in[5];
    const float* b1      = (const float*)d_in[6];
    const float* w2      = (const float*)d_in[7];
    const float* b2      = (const float*)d_in[8];
    const float* gate_w  = (const float*)d_in[9];
    const float* wih0    = (const float*)d_in[11];
    const float* bih0    = (const float*)d_in[13];
    const float* bhh0    = (const float*)d_in[14];
    const float* wih1    = (const float*)d_in[15];
    const float* bih1    = (const float*)d_in[17];
    const float* bhh1    = (const float*)d_in[18];
    const float* pw      = (const float*)d_in[19];
    const float* pb      = (const float*)d_in[20];
    float* out = (float*)d_out;

    const int N = in_sizes[2];        // 50000 nodes
    const int E = in_sizes[1] / 2;    // 800000 edges
    const int G = N_GRAPHS;           // 256 graphs

    char* base = (char*)d_ws;
    size_t off = 0;
    auto alloc = [&](size_t bytes) -> char* {
        char* p = base + off;
        off = (off + bytes + 255) & ~(size_t)255;
        return p;
    };
    ushort_t* bufA  = (ushort_t*)alloc((size_t)N * 512 * 2);  // xs / final x (bf16)
    ushort_t* bufB  = (ushort_t*)alloc((size_t)N * 512 * 2);  // agg (bf16)
    float* dinv     = (float*)alloc((size_t)N * 4);
    // zeroed range: gateArr, bars, counts (single memset)
    float* gateArr  = (float*)alloc((size_t)N * 4);
    int*   bars     = (int*)alloc((size_t)8 * 4);
    int*   counts   = (int*)alloc((size_t)(N + 1) * 4);
    int*   cursor   = (int*)alloc((size_t)(N + 1) * 4);
    int*   rowptr   = (int*)alloc((size_t)(N + 1) * 4);
    int*   bsums    = (int*)alloc((size_t)256 * 4);
    int*   col      = (int*)alloc((size_t)E * 4);
    ushort_t* wt0   = (ushort_t*)alloc((size_t)128 * 64 * 2);
    ushort_t* wt1   = (ushort_t*)alloc((size_t)256 * 128 * 2);
    ushort_t* wt2   = (ushort_t*)alloc((size_t)512 * 256 * 2);
    ushort_t* ih0H  = (ushort_t*)alloc((size_t)768 * 512 * 2);
    ushort_t* ih0L  = (ushort_t*)alloc((size_t)768 * 512 * 2);
    ushort_t* ih1H  = (ushort_t*)alloc((size_t)768 * 256 * 2);
    ushort_t* ih1L  = (ushort_t*)alloc((size_t)768 * 256 * 2);
    ushort_t* pwH   = (ushort_t*)alloc((size_t)512 * 256 * 2);
    ushort_t* pwL   = (ushort_t*)alloc((size_t)512 * 256 * 2);
    ushort_t* embH  = (ushort_t*)alloc((size_t)G * 512 * 2);
    ushort_t* embL  = (ushort_t*)alloc((size_t)G * 512 * 2);
    ushort_t* h1H   = (ushort_t*)alloc((size_t)G * 256 * 2);
    ushort_t* h1L   = (ushort_t*)alloc((size_t)G * 256 * 2);
    ushort_t* h2H   = (ushort_t*)alloc((size_t)G * 256 * 2);
    ushort_t* h2L   = (ushort_t*)alloc((size_t)G * 256 * 2);
    float* gi       = (float*)alloc((size_t)G * 768 * 4);
    (void)ws_size; (void)n_in; (void)out_size;

    const int* src = ei;
    const int* dst = ei + E;

    const int nb = (N + SCAN_CHUNK - 1) / SCAN_CHUNK;   // 25 for N=50000

    // zero gateArr + bars + counts in one shot (adjacent in carve-up)
    size_t zbytes = (size_t)((char*)counts - (char*)gateArr) + (size_t)(N + 1) * 4;
    hipMemsetAsync(gateArr, 0, zbytes, stream);

    // CSR build + dinv
    k_hist<<<(E + 255) / 256, 256, 0, stream>>>(dst, counts, E);
    k_scan1<<<nb, 256, 0, stream>>>(counts, rowptr, bsums, dinv, N);
    k_scan3<<<nb, 256, 0, stream>>>(rowptr, cursor, bsums, N, nb);

    // packed: fill + prescale + wt_all + split_all (all independent)
    int nf = (E + 255) / 256;
    int np = (N * 8 + 255) / 256;
    int nw = (172032 + 255) / 256;
    int ns = (720896 + 255) / 256;
    k_pack<<<nf + np + nw + ns, 256, 0, stream>>>(
        src, dst, cursor, col, E,
        (const float4*)x, dinv, (uint4*)bufA, N,
        w0, w1, w2, wt0, wt1, wt2,
        wih0, wih1, pw, ih0H, ih0L, ih1H, ih1L, pwH, pwL,
        nf, np, nw);

    int mBlocks = (N + 63) / 64;

    // layer 1: gather D=64, GEMM 64->128 (relu * dinv)
    k_gather_bf16<<<(N * 8 + 255) / 256, 256, 0, stream>>>((const uint4*)bufA, rowptr, col, dinv, (uint4*)bufB, N, 3);
    k_gemm_mfma<<<dim3(mBlocks, 2), 256, 0, stream>>>(bufB, wt0, b0, dinv, bufA, N, 64, 128, 1, nullptr, nullptr);

    // layer 2: gather D=128, GEMM 128->256 (relu * dinv)
    k_gather_bf16<<<(N * 16 + 255) / 256, 256, 0, stream>>>((const uint4*)bufA, rowptr, col, dinv, (uint4*)bufB, N, 4);
    k_gemm_mfma<<<dim3(mBlocks, 4), 256, 0, stream>>>(bufB, wt1, b1, dinv, bufA, N, 128, 256, 1, nullptr, nullptr);

    // layer 3: gather D=256, GEMM 256->512 (relu; fused gate partial dots)
    k_gather_bf16<<<(N * 32 + 255) / 256, 256, 0, stream>>>((const uint4*)bufA, rowptr, col, dinv, (uint4*)bufB, N, 5);
    k_gemm_mfma<<<dim3(mBlocks, 8), 256, 0, stream>>>(bufB, wt2, b2, dinv, bufA, N, 256, 512, 0, gate_w, gateArr);

    // fused tail: softmax+emb -> GRU0 -> GRU1 -> proj
    k_tail<<<G, 256, 0, stream>>>((const uint_t*)bufA, gateArr, batch, N,
                                  ih0H, ih0L, ih1H, ih1L, pwH, pwL,
                                  bih0, bhh0, bih1, bhh1, pb,
                                  embH, embL, h1H, h1L, h2H, h2L, gi, out, bars);
}

// Round 11
// 435.843 us; speedup vs baseline: 1.4987x; 1.4987x over previous
//
#include <hip/hip_runtime.h>

// ---------------------------------------------------------------------------
// TraceLevelEncoder: 3x GCNConv -> segment-softmax attention pool -> GRU(2,seq=1,h0=0) -> proj
// Round 11: REVERT tail fusion (R10: 5 grid barriers @ ~50us each — spin
//           atomics across 8 non-coherent XCD L2s are ~10x a launch gap).
//           Back to R9's separate tail kernels; keep k_pack merge.
// ---------------------------------------------------------------------------

#define N_GRAPHS 256
#define GRU_H 256
#define SCAN_CHUNK 2048   // 256 threads x 8 elements

typedef __attribute__((ext_vector_type(8))) short short8;   // 8 bf16 (4 VGPRs)
typedef __attribute__((ext_vector_type(4))) float floatx4;  // 4 fp32 acc

typedef unsigned short ushort_t;
typedef unsigned int uint_t;

__device__ __forceinline__ float bflo(uint_t u) { return __uint_as_float(u << 16); }
__device__ __forceinline__ float bfhi(uint_t u) { return __uint_as_float(u & 0xffff0000u); }
__device__ __forceinline__ uint_t f2bf(float f) {           // RNE
    uint_t u = __float_as_uint(f);
    return (u + 0x7fffu + ((u >> 16) & 1u)) >> 16;
}
__device__ __forceinline__ uint_t pack2(float a, float b) {
    return f2bf(a) | (f2bf(b) << 16);
}

// ---- CSR build ------------------------------------------------------------

__global__ void k_hist(const int* __restrict__ dst, int* __restrict__ counts, int E) {
    int e = blockIdx.x * blockDim.x + threadIdx.x;
    if (e < E) atomicAdd(&counts[dst[e]], 1);
}

__global__ __launch_bounds__(256) void k_scan1(const int* __restrict__ counts,
                                               int* __restrict__ rowptr,
                                               int* __restrict__ bsums,
                                               float* __restrict__ dinv, int n) {
    int b = blockIdx.x, t = threadIdx.x;
    int base = b * SCAN_CHUNK + t * 8;
    int v[8];
    int s = 0;
#pragma unroll
    for (int j = 0; j < 8; ++j) {
        int i = base + j;
        int c = (i < n) ? counts[i] : 0;
        v[j] = s;            // exclusive within thread
        s += c;
        if (i < n) dinv[i] = rsqrtf((float)(c + 1));  // +1 self loop
    }
    __shared__ int sd[256];
    sd[t] = s;
    __syncthreads();
    for (int off = 1; off < 256; off <<= 1) {
        int tmp = (t >= off) ? sd[t - off] : 0;
        __syncthreads();
        sd[t] += tmp;
        __syncthreads();
    }
    int texcl = sd[t] - s;
    if (t == 255) bsums[b] = sd[255];
#pragma unroll
    for (int j = 0; j < 8; ++j) {
        int i = base + j;
        if (i < n) rowptr[i] = texcl + v[j];
    }
}

// scan3 (scan2 folded): each block derives its own offset from bsums
__global__ __launch_bounds__(256) void k_scan3(int* __restrict__ rowptr,
                                               int* __restrict__ cursor,
                                               const int* __restrict__ bsums,
                                               int n, int nb) {
    int b = blockIdx.x, t = threadIdx.x;
    __shared__ int s_off;
    if (t == 0) {
        int off = 0, tot = 0;
        for (int i = 0; i < nb; ++i) {
            int v = bsums[i];
            if (i < b) off += v;
            tot += v;
        }
        s_off = off;
        if (b == 0) rowptr[n] = tot;
    }
    __syncthreads();
    int off = s_off;
    int base = b * SCAN_CHUNK + t * 8;
#pragma unroll
    for (int j = 0; j < 8; ++j) {
        int i = base + j;
        if (i < n) { int r = rowptr[i] + off; rowptr[i] = r; cursor[i] = r; }
    }
}

// ---- packed independent kernels: fill | prescale | wt_all | split_all -----

__global__ __launch_bounds__(256) void k_pack(
    const int* __restrict__ src, const int* __restrict__ dst,
    int* __restrict__ cursor, int* __restrict__ col, int E,
    const float4* __restrict__ x, const float* __restrict__ dinv,
    uint4* __restrict__ xs, int N,
    const float* __restrict__ w0, const float* __restrict__ w1,
    const float* __restrict__ w2, ushort_t* __restrict__ wt0,
    ushort_t* __restrict__ wt1, ushort_t* __restrict__ wt2,
    const float* __restrict__ wih0, const float* __restrict__ wih1,
    const float* __restrict__ pw,
    ushort_t* __restrict__ sh0, ushort_t* __restrict__ sl0,
    ushort_t* __restrict__ sh1, ushort_t* __restrict__ sl1,
    ushort_t* __restrict__ sh2, ushort_t* __restrict__ sl2,
    int nf, int np, int nw) {
    int b = blockIdx.x, t = threadIdx.x;
    if (b < nf) {
        int e = b * 256 + t;
        if (e < E) {
            int pos = atomicAdd(&cursor[dst[e]], 1);
            col[pos] = src[e];
        }
    } else if (b < nf + np) {
        int idx = (b - nf) * 256 + t;   // chunk of 8 over N*64
        int n = idx >> 3;
        if (n < N) {
            float dn = dinv[n];
            float4 v0 = x[idx * 2], v1 = x[idx * 2 + 1];
            uint4 o;
            o.x = pack2(v0.x * dn, v0.y * dn);
            o.y = pack2(v0.z * dn, v0.w * dn);
            o.z = pack2(v1.x * dn, v1.y * dn);
            o.w = pack2(v1.z * dn, v1.w * dn);
            xs[idx] = o;
        }
    } else if (b < nf + np + nw) {
        int idx = (b - nf - np) * 256 + t;
        if (idx < 8192) {
            int k = idx >> 7, n = idx & 127;
            wt0[(size_t)n * 64 + k] = (ushort_t)f2bf(w0[idx]);
        } else if (idx < 40960) {
            int i = idx - 8192;
            int k = i >> 8, n = i & 255;
            wt1[(size_t)n * 128 + k] = (ushort_t)f2bf(w1[i]);
        } else if (idx < 172032) {
            int i = idx - 40960;
            int k = i >> 9, n = i & 511;
            wt2[(size_t)n * 256 + k] = (ushort_t)f2bf(w2[i]);
        }
    } else {
        int idx = (b - nf - np - nw) * 256 + t;
        const float* s; ushort_t* H; ushort_t* L; int i;
        if (idx < 393216)      { s = wih0; H = sh0; L = sl0; i = idx; }
        else if (idx < 589824) { s = wih1; H = sh1; L = sl1; i = idx - 393216; }
        else if (idx < 720896) { s = pw;   H = sh2; L = sl2; i = idx - 589824; }
        else return;
        float v = s[i];
        uint_t h = f2bf(v);
        H[i] = (ushort_t)h;
        L[i] = (ushort_t)f2bf(v - __uint_as_float(h << 16));
    }
}

// ---- Edge aggregation (gather over CSR), bf16, fp32 accum, 8x unrolled ----

__device__ __forceinline__ void acc8(float& a0, float& a1, float& a2, float& a3,
                                     float& a4, float& a5, float& a6, float& a7,
                                     const uint4& v) {
    a0 += bflo(v.x); a1 += bfhi(v.x); a2 += bflo(v.y); a3 += bfhi(v.y);
    a4 += bflo(v.z); a5 += bfhi(v.z); a6 += bflo(v.w); a7 += bfhi(v.w);
}

__global__ void k_gather_bf16(const uint4* __restrict__ xs, const int* __restrict__ rp,
                              const int* __restrict__ col, const float* __restrict__ dinv,
                              uint4* __restrict__ agg, int N, int shift /*log2(D/8)*/) {
    int idx = blockIdx.x * blockDim.x + threadIdx.x;
    int n = idx >> shift;
    if (n >= N) return;
    int c = idx & ((1 << shift) - 1);
    int C8 = 1 << shift;
    int a = rp[n], b = rp[n + 1];
    uint4 u = xs[(size_t)n * C8 + c];   // self loop (pre-scaled by dinv[n])
    float a0 = bflo(u.x), a1 = bfhi(u.x), a2 = bflo(u.y), a3 = bfhi(u.y);
    float a4 = bflo(u.z), a5 = bfhi(u.z), a6 = bflo(u.w), a7 = bfhi(u.w);
    int k = a;
    for (; k + 8 <= b; k += 8) {
        int ci[8];
#pragma unroll
        for (int j = 0; j < 8; ++j) ci[j] = col[k + j];
        uint4 v[8];
#pragma unroll
        for (int j = 0; j < 8; ++j) v[j] = xs[(size_t)ci[j] * C8 + c];
#pragma unroll
        for (int j = 0; j < 8; ++j)
            acc8(a0, a1, a2, a3, a4, a5, a6, a7, v[j]);
    }
    for (; k + 4 <= b; k += 4) {
        int ci[4];
#pragma unroll
        for (int j = 0; j < 4; ++j) ci[j] = col[k + j];
        uint4 v[4];
#pragma unroll
        for (int j = 0; j < 4; ++j) v[j] = xs[(size_t)ci[j] * C8 + c];
#pragma unroll
        for (int j = 0; j < 4; ++j)
            acc8(a0, a1, a2, a3, a4, a5, a6, a7, v[j]);
    }
    for (; k < b; ++k) {
        uint4 v = xs[(size_t)col[k] * C8 + c];
        acc8(a0, a1, a2, a3, a4, a5, a6, a7, v);
    }
    float dn = dinv[n];
    uint4 o;
    o.x = pack2(a0 * dn, a1 * dn);
    o.y = pack2(a2 * dn, a3 * dn);
    o.z = pack2(a4 * dn, a5 * dn);
    o.w = pack2(a6 * dn, a7 * dn);
    agg[idx] = o;
}

// ---- MFMA bf16 GEMM (GCN layers): C = postproc(A @ Wt^T + bias) -----------
// 64x64 block tile, BK=64, 4 waves 2x2, each wave 32x32 via 2x2 MFMAs.
// Optional fused gate: gateArr[row] += dot(relu'd row-slice, gate_w-slice).

__global__ __launch_bounds__(256) void k_gemm_mfma(
    const ushort_t* __restrict__ A, const ushort_t* __restrict__ Wt,
    const float* __restrict__ bias, const float* __restrict__ dinv,
    ushort_t* __restrict__ C, int M, int K, int Nout, int scale_out,
    const float* __restrict__ gate_w, float* __restrict__ gateArr) {
    __shared__ ushort_t As[64 * 72];   // stride 72 bf16 (144B rows, 16B-aligned)
    __shared__ ushort_t Bs[64 * 72];
    int tid = threadIdx.x;
    int wave = tid >> 6, lane = tid & 63;
    int quad = lane >> 4, lr = lane & 15;
    int wm = (wave & 1) * 32, wn = (wave >> 1) * 32;
    int bm = blockIdx.x * 64, bn = blockIdx.y * 64;

    floatx4 zero = {0.f, 0.f, 0.f, 0.f};
    floatx4 acc00 = zero, acc01 = zero, acc10 = zero, acc11 = zero;

    int r0 = tid >> 3,         ko0 = (tid & 7) * 8;
    int r1 = (tid + 256) >> 3, ko1 = ((tid + 256) & 7) * 8;

    for (int k0 = 0; k0 < K; k0 += 64) {
        int ar0 = min(bm + r0, M - 1);
        int ar1 = min(bm + r1, M - 1);
        uint4 av0 = *(const uint4*)(A + (size_t)ar0 * K + k0 + ko0);
        uint4 av1 = *(const uint4*)(A + (size_t)ar1 * K + k0 + ko1);
        uint4 bv0 = *(const uint4*)(Wt + (size_t)(bn + r0) * K + k0 + ko0);
        uint4 bv1 = *(const uint4*)(Wt + (size_t)(bn + r1) * K + k0 + ko1);
        __syncthreads();   // prev iter LDS reads done
        *(uint4*)&As[r0 * 72 + ko0] = av0;
        *(uint4*)&As[r1 * 72 + ko1] = av1;
        *(uint4*)&Bs[r0 * 72 + ko0] = bv0;
        *(uint4*)&Bs[r1 * 72 + ko1] = bv1;
        __syncthreads();
#pragma unroll
        for (int ks = 0; ks < 2; ++ks) {
            short8 af0 = *(short8*)&As[(wm + lr) * 72 + ks * 32 + quad * 8];
            short8 af1 = *(short8*)&As[(wm + 16 + lr) * 72 + ks * 32 + quad * 8];
            short8 bf0 = *(short8*)&Bs[(wn + lr) * 72 + ks * 32 + quad * 8];
            short8 bf1 = *(short8*)&Bs[(wn + 16 + lr) * 72 + ks * 32 + quad * 8];
            acc00 = __builtin_amdgcn_mfma_f32_16x16x32_bf16(af0, bf0, acc00, 0, 0, 0);
            acc01 = __builtin_amdgcn_mfma_f32_16x16x32_bf16(af0, bf1, acc01, 0, 0, 0);
            acc10 = __builtin_amdgcn_mfma_f32_16x16x32_bf16(af1, bf0, acc10, 0, 0, 0);
            acc11 = __builtin_amdgcn_mfma_f32_16x16x32_bf16(af1, bf1, acc11, 0, 0, 0);
        }
    }

    // epilogue: C/D layout col=lane&15, row=quad*4+r (m89-verified)
    float gwv[2] = {0.f, 0.f};
    if (gate_w) {
        gwv[0] = gate_w[bn + wn + lr];
        gwv[1] = gate_w[bn + wn + 16 + lr];
    }
    float pg[2][4] = {};
#pragma unroll
    for (int mi = 0; mi < 2; ++mi) {
#pragma unroll
        for (int ni = 0; ni < 2; ++ni) {
            floatx4 acc = (mi == 0) ? (ni == 0 ? acc00 : acc01)
                                    : (ni == 0 ? acc10 : acc11);
            int col = bn + wn + ni * 16 + lr;
            float bcol = bias[col];
#pragma unroll
            for (int r = 0; r < 4; ++r) {
                int row = bm + wm + mi * 16 + quad * 4 + r;
                if (row < M) {
                    float v = acc[r] + bcol;
                    v = fmaxf(v, 0.0f);
                    if (gate_w) pg[mi][r] += v * gwv[ni];
                    if (scale_out) v *= dinv[row];
                    C[(size_t)row * Nout + col] = (ushort_t)f2bf(v);
                }
            }
        }
    }
    if (gate_w) {
#pragma unroll
        for (int mi = 0; mi < 2; ++mi) {
#pragma unroll
            for (int r = 0; r < 4; ++r) {
                float p = pg[mi][r];
                p += __shfl_down(p, 8, 16);
                p += __shfl_down(p, 4, 16);
                p += __shfl_down(p, 2, 16);
                p += __shfl_down(p, 1, 16);
                if (lr == 0) {
                    int row = bm + wm + mi * 16 + quad * 4 + r;
                    if (row < M) atomicAdd(&gateArr[row], p);
                }
            }
        }
    }
}

// ---- split-precision MFMA GEMM (GRU/proj): C_f32 = A @ W^T (+bias) --------

__global__ __launch_bounds__(256) void k_gemm3(
    const ushort_t* __restrict__ Ahi, const ushort_t* __restrict__ Alo,
    const ushort_t* __restrict__ Whi, const ushort_t* __restrict__ Wlo,
    const float* __restrict__ bias, float* __restrict__ C,
    int M, int K, int Nout) {
    __shared__ ushort_t AsH[64 * 72];
    __shared__ ushort_t AsL[64 * 72];
    __shared__ ushort_t BsH[64 * 72];
    __shared__ ushort_t BsL[64 * 72];
    int tid = threadIdx.x;
    int wave = tid >> 6, lane = tid & 63;
    int quad = lane >> 4, lr = lane & 15;
    int wm = (wave & 1) * 32, wn = (wave >> 1) * 32;
    int bm = blockIdx.x * 64, bn = blockIdx.y * 64;

    floatx4 zero = {0.f, 0.f, 0.f, 0.f};
    floatx4 acc00 = zero, acc01 = zero, acc10 = zero, acc11 = zero;

    int r0 = tid >> 3,         ko0 = (tid & 7) * 8;
    int r1 = (tid + 256) >> 3, ko1 = ((tid + 256) & 7) * 8;

    for (int k0 = 0; k0 < K; k0 += 64) {
        int ar0 = min(bm + r0, M - 1);
        int ar1 = min(bm + r1, M - 1);
        size_t a0o = (size_t)ar0 * K + k0 + ko0, a1o = (size_t)ar1 * K + k0 + ko1;
        size_t b0o = (size_t)(bn + r0) * K + k0 + ko0, b1o = (size_t)(bn + r1) * K + k0 + ko1;
        uint4 ah0 = *(const uint4*)(Ahi + a0o), ah1 = *(const uint4*)(Ahi + a1o);
        uint4 al0 = *(const uint4*)(Alo + a0o), al1 = *(const uint4*)(Alo + a1o);
        uint4 bh0 = *(const uint4*)(Whi + b0o), bh1 = *(const uint4*)(Whi + b1o);
        uint4 bl0 = *(const uint4*)(Wlo + b0o), bl1 = *(const uint4*)(Wlo + b1o);
        __syncthreads();
        *(uint4*)&AsH[r0 * 72 + ko0] = ah0; *(uint4*)&AsH[r1 * 72 + ko1] = ah1;
        *(uint4*)&AsL[r0 * 72 + ko0] = al0; *(uint4*)&AsL[r1 * 72 + ko1] = al1;
        *(uint4*)&BsH[r0 * 72 + ko0] = bh0; *(uint4*)&BsH[r1 * 72 + ko1] = bh1;
        *(uint4*)&BsL[r0 * 72 + ko0] = bl0; *(uint4*)&BsL[r1 * 72 + ko1] = bl1;
        __syncthreads();
#pragma unroll
        for (int ks = 0; ks < 2; ++ks) {
            int a0i = (wm + lr) * 72 + ks * 32 + quad * 8;
            int a1i = (wm + 16 + lr) * 72 + ks * 32 + quad * 8;
            int b0i = (wn + lr) * 72 + ks * 32 + quad * 8;
            int b1i = (wn + 16 + lr) * 72 + ks * 32 + quad * 8;
            short8 afh0 = *(short8*)&AsH[a0i], afh1 = *(short8*)&AsH[a1i];
            short8 afl0 = *(short8*)&AsL[a0i], afl1 = *(short8*)&AsL[a1i];
            short8 bfh0 = *(short8*)&BsH[b0i], bfh1 = *(short8*)&BsH[b1i];
            short8 bfl0 = *(short8*)&BsL[b0i], bfl1 = *(short8*)&BsL[b1i];
            acc00 = __builtin_amdgcn_mfma_f32_16x16x32_bf16(afh0, bfh0, acc00, 0, 0, 0);
            acc00 = __builtin_amdgcn_mfma_f32_16x16x32_bf16(afh0, bfl0, acc00, 0, 0, 0);
            acc00 = __builtin_amdgcn_mfma_f32_16x16x32_bf16(afl0, bfh0, acc00, 0, 0, 0);
            acc01 = __builtin_amdgcn_mfma_f32_16x16x32_bf16(afh0, bfh1, acc01, 0, 0, 0);
            acc01 = __builtin_amdgcn_mfma_f32_16x16x32_bf16(afh0, bfl1, acc01, 0, 0, 0);
            acc01 = __builtin_amdgcn_mfma_f32_16x16x32_bf16(afl0, bfh1, acc01, 0, 0, 0);
            acc10 = __builtin_amdgcn_mfma_f32_16x16x32_bf16(afh1, bfh0, acc10, 0, 0, 0);
            acc10 = __builtin_amdgcn_mfma_f32_16x16x32_bf16(afh1, bfl0, acc10, 0, 0, 0);
            acc10 = __builtin_amdgcn_mfma_f32_16x16x32_bf16(afl1, bfh0, acc10, 0, 0, 0);
            acc11 = __builtin_amdgcn_mfma_f32_16x16x32_bf16(afh1, bfh1, acc11, 0, 0, 0);
            acc11 = __builtin_amdgcn_mfma_f32_16x16x32_bf16(afh1, bfl1, acc11, 0, 0, 0);
            acc11 = __builtin_amdgcn_mfma_f32_16x16x32_bf16(afl1, bfh1, acc11, 0, 0, 0);
        }
    }

#pragma unroll
    for (int mi = 0; mi < 2; ++mi) {
#pragma unroll
        for (int ni = 0; ni < 2; ++ni) {
            floatx4 acc = (mi == 0) ? (ni == 0 ? acc00 : acc01)
                                    : (ni == 0 ? acc10 : acc11);
            int col = bn + wn + ni * 16 + lr;
            float bcol = bias ? bias[col] : 0.0f;
#pragma unroll
            for (int r = 0; r < 4; ++r) {
                int row = bm + wm + mi * 16 + quad * 4 + r;
                if (row < M)
                    C[(size_t)row * Nout + col] = acc[r] + bcol;
            }
        }
    }
}

// ---- GRU gate epilogue (h=0: gh = bhh exactly, h' = (1-z)*n) --------------

__global__ void k_gru_ep(const float* __restrict__ gi, const float* __restrict__ bih,
                         const float* __restrict__ bhh,
                         ushort_t* __restrict__ hhi, ushort_t* __restrict__ hlo, int G) {
    int idx = blockIdx.x * blockDim.x + threadIdx.x;
    int g = idx >> 8, j = idx & 255;
    if (g >= G) return;
    const float* row = gi + (size_t)g * 768;
    float ir = row[j]       + bih[j]       + bhh[j];
    float iz = row[j + 256] + bih[j + 256] + bhh[j + 256];
    float in = row[j + 512] + bih[j + 512];
    float r = 1.0f / (1.0f + expf(-ir));
    float z = 1.0f / (1.0f + expf(-iz));
    float nn = tanhf(in + r * bhh[j + 512]);
    float h = (1.0f - z) * nn;
    uint_t hi = f2bf(h);
    hhi[idx] = (ushort_t)hi;
    hlo[idx] = (ushort_t)f2bf(h - __uint_as_float(hi << 16));
}

// ---- segment softmax + weighted sum -> graph emb (bf16 split pair) --------

__global__ __launch_bounds__(256) void k_softmax_emb(
    const uint_t* __restrict__ x /*bf16 pairs*/, const float* __restrict__ gate,
    const int* __restrict__ batch, int N,
    ushort_t* __restrict__ embH, ushort_t* __restrict__ embL) {
    int g = blockIdx.x;
    int s, e;
    {
        int lo = 0, hi = N;
        while (lo < hi) { int mid = (lo + hi) >> 1; if (batch[mid] < g) lo = mid + 1; else hi = mid; }
        s = lo;
        lo = s; hi = N;
        while (lo < hi) { int mid = (lo + hi) >> 1; if (batch[mid] < g + 1) lo = mid + 1; else hi = mid; }
        e = lo;
    }
    __shared__ float red[256];
    __shared__ float sal[256];
    int tid = threadIdx.x;
    float m = -INFINITY;
    for (int i = s + tid; i < e; i += 256) m = fmaxf(m, gate[i]);
    red[tid] = m; __syncthreads();
    for (int off = 128; off > 0; off >>= 1) {
        if (tid < off) red[tid] = fmaxf(red[tid], red[tid + off]);
        __syncthreads();
    }
    m = red[0]; __syncthreads();
    float ssum = 0.f;
    for (int i = s + tid; i < e; i += 256) ssum += expf(gate[i] - m);
    red[tid] = ssum; __syncthreads();
    for (int off = 128; off > 0; off >>= 1) {
        if (tid < off) red[tid] += red[tid + off];
        __syncthreads();
    }
    float denom = red[0];
    float inv = (denom > 0.f) ? 1.0f / denom : 0.0f;
    float acc0 = 0.f, acc1 = 0.f;
    for (int base = s; base < e; base += 256) {
        int i = base + tid;
        __syncthreads();
        sal[tid] = (i < e) ? expf(gate[i] - m) * inv : 0.0f;
        __syncthreads();
        int cnt = min(256, e - base);
        for (int k = 0; k < cnt; ++k) {
            float a = sal[k];
            uint_t u = x[(size_t)(base + k) * 256 + tid];
            acc0 += a * bflo(u);
            acc1 += a * bfhi(u);
        }
    }
    int i0 = g * 512 + tid * 2;
    uint_t h0 = f2bf(acc0);
    uint_t h1 = f2bf(acc1);
    embH[i0]     = (ushort_t)h0;
    embH[i0 + 1] = (ushort_t)h1;
    embL[i0]     = (ushort_t)f2bf(acc0 - __uint_as_float(h0 << 16));
    embL[i0 + 1] = (ushort_t)f2bf(acc1 - __uint_as_float(h1 << 16));
}

// ---------------------------------------------------------------------------

extern "C" void kernel_launch(void* const* d_in, const int* in_sizes, int n_in,
                              void* d_out, int out_size, void* d_ws, size_t ws_size,
                              hipStream_t stream) {
    const float* x       = (const float*)d_in[0];
    const int*   ei      = (const int*)d_in[1];
    const int*   batch   = (const int*)d_in[2];
    const float* w0      = (const float*)d_in[3];
    const float* b0      = (const float*)d_in[4];
    const float* w1      = (const float*)d_in[5];
    const float* b1      = (const float*)d_in[6];
    const float* w2      = (const float*)d_in[7];
    const float* b2      = (const float*)d_in[8];
    const float* gate_w  = (const float*)d_in[9];
    const float* wih0    = (const float*)d_in[11];
    const float* bih0    = (const float*)d_in[13];
    const float* bhh0    = (const float*)d_in[14];
    const float* wih1    = (const float*)d_in[15];
    const float* bih1    = (const float*)d_in[17];
    const float* bhh1    = (const float*)d_in[18];
    const float* pw      = (const float*)d_in[19];
    const float* pb      = (const float*)d_in[20];
    float* out = (float*)d_out;

    const int N = in_sizes[2];        // 50000 nodes
    const int E = in_sizes[1] / 2;    // 800000 edges
    const int G = N_GRAPHS;           // 256 graphs

    char* base = (char*)d_ws;
    size_t off = 0;
    auto alloc = [&](size_t bytes) -> char* {
        char* p = base + off;
        off = (off + bytes + 255) & ~(size_t)255;
        return p;
    };
    ushort_t* bufA  = (ushort_t*)alloc((size_t)N * 512 * 2);  // xs / final x (bf16)
    ushort_t* bufB  = (ushort_t*)alloc((size_t)N * 512 * 2);  // agg (bf16)
    float* dinv     = (float*)alloc((size_t)N * 4);
    // zeroed range: gateArr, counts (single memset)
    float* gateArr  = (float*)alloc((size_t)N * 4);
    int*   counts   = (int*)alloc((size_t)(N + 1) * 4);
    int*   cursor   = (int*)alloc((size_t)(N + 1) * 4);
    int*   rowptr   = (int*)alloc((size_t)(N + 1) * 4);
    int*   bsums    = (int*)alloc((size_t)256 * 4);
    int*   col      = (int*)alloc((size_t)E * 4);
    ushort_t* wt0   = (ushort_t*)alloc((size_t)128 * 64 * 2);
    ushort_t* wt1   = (ushort_t*)alloc((size_t)256 * 128 * 2);
    ushort_t* wt2   = (ushort_t*)alloc((size_t)512 * 256 * 2);
    ushort_t* ih0H  = (ushort_t*)alloc((size_t)768 * 512 * 2);
    ushort_t* ih0L  = (ushort_t*)alloc((size_t)768 * 512 * 2);
    ushort_t* ih1H  = (ushort_t*)alloc((size_t)768 * 256 * 2);
    ushort_t* ih1L  = (ushort_t*)alloc((size_t)768 * 256 * 2);
    ushort_t* pwH   = (ushort_t*)alloc((size_t)512 * 256 * 2);
    ushort_t* pwL   = (ushort_t*)alloc((size_t)512 * 256 * 2);
    ushort_t* embH  = (ushort_t*)alloc((size_t)G * 512 * 2);
    ushort_t* embL  = (ushort_t*)alloc((size_t)G * 512 * 2);
    ushort_t* h1H   = (ushort_t*)alloc((size_t)G * 256 * 2);
    ushort_t* h1L   = (ushort_t*)alloc((size_t)G * 256 * 2);
    ushort_t* h2H   = (ushort_t*)alloc((size_t)G * 256 * 2);
    ushort_t* h2L   = (ushort_t*)alloc((size_t)G * 256 * 2);
    float* gi       = (float*)alloc((size_t)G * 768 * 4);
    (void)ws_size; (void)n_in; (void)out_size;

    const int* src = ei;
    const int* dst = ei + E;

    const int nb = (N + SCAN_CHUNK - 1) / SCAN_CHUNK;   // 25 for N=50000

    // zero gateArr + counts in one shot (adjacent in carve-up)
    size_t zbytes = (size_t)((char*)counts - (char*)gateArr) + (size_t)(N + 1) * 4;
    hipMemsetAsync(gateArr, 0, zbytes, stream);

    // CSR build + dinv
    k_hist<<<(E + 255) / 256, 256, 0, stream>>>(dst, counts, E);
    k_scan1<<<nb, 256, 0, stream>>>(counts, rowptr, bsums, dinv, N);
    k_scan3<<<nb, 256, 0, stream>>>(rowptr, cursor, bsums, N, nb);

    // packed: fill + prescale + wt_all + split_all (all independent)
    int nf = (E + 255) / 256;
    int np = (N * 8 + 255) / 256;
    int nw = (172032 + 255) / 256;
    int ns = (720896 + 255) / 256;
    k_pack<<<nf + np + nw + ns, 256, 0, stream>>>(
        src, dst, cursor, col, E,
        (const float4*)x, dinv, (uint4*)bufA, N,
        w0, w1, w2, wt0, wt1, wt2,
        wih0, wih1, pw, ih0H, ih0L, ih1H, ih1L, pwH, pwL,
        nf, np, nw);

    int mBlocks = (N + 63) / 64;

    // layer 1: gather D=64, GEMM 64->128 (relu * dinv)
    k_gather_bf16<<<(N * 8 + 255) / 256, 256, 0, stream>>>((const uint4*)bufA, rowptr, col, dinv, (uint4*)bufB, N, 3);
    k_gemm_mfma<<<dim3(mBlocks, 2), 256, 0, stream>>>(bufB, wt0, b0, dinv, bufA, N, 64, 128, 1, nullptr, nullptr);

    // layer 2: gather D=128, GEMM 128->256 (relu * dinv)
    k_gather_bf16<<<(N * 16 + 255) / 256, 256, 0, stream>>>((const uint4*)bufA, rowptr, col, dinv, (uint4*)bufB, N, 4);
    k_gemm_mfma<<<dim3(mBlocks, 4), 256, 0, stream>>>(bufB, wt1, b1, dinv, bufA, N, 128, 256, 1, nullptr, nullptr);

    // layer 3: gather D=256, GEMM 256->512 (relu; fused gate partial dots)
    k_gather_bf16<<<(N * 32 + 255) / 256, 256, 0, stream>>>((const uint4*)bufA, rowptr, col, dinv, (uint4*)bufB, N, 5);
    k_gemm_mfma<<<dim3(mBlocks, 8), 256, 0, stream>>>(bufB, wt2, b2, dinv, bufA, N, 256, 512, 0, gate_w, gateArr);

    // attention pool (gstart + emb-split folded in; gate_b cancels in softmax)
    k_softmax_emb<<<G, 256, 0, stream>>>((const uint_t*)bufA, gateArr, batch, N, embH, embL);

    // GRU layer 0: gi = emb @ wih0^T  (M=256, K=512, N=768), then gate math
    k_gemm3<<<dim3(G / 64, 12), 256, 0, stream>>>(embH, embL, ih0H, ih0L, nullptr, gi, G, 512, 768);
    k_gru_ep<<<G, 256, 0, stream>>>(gi, bih0, bhh0, h1H, h1L, G);

    // GRU layer 1: gi = h1 @ wih1^T  (M=256, K=256, N=768)
    k_gemm3<<<dim3(G / 64, 12), 256, 0, stream>>>(h1H, h1L, ih1H, ih1L, nullptr, gi, G, 256, 768);
    k_gru_ep<<<G, 256, 0, stream>>>(gi, bih1, bhh1, h2H, h2L, G);

    // projection: out = h2 @ pw^T + pb  (M=256, K=256, N=512)
    k_gemm3<<<dim3(G / 64, 8), 256, 0, stream>>>(h2H, h2L, pwH, pwL, pb, out, G, 256, 512);
}

// Round 12
// 432.323 us; speedup vs baseline: 1.5109x; 1.0081x over previous
//
#include <hip/hip_runtime.h>

// ---------------------------------------------------------------------------
// TraceLevelEncoder: 3x GCNConv -> segment-softmax attention pool -> GRU(2,seq=1,h0=0) -> proj
// Round 12: XCD-aware grid swizzle for GCN GEMMs. R11's (bm,bn) grid re-reads
//   A once per bn-column across non-coherent XCD L2s (FETCH 101 MB vs 26
//   ideal). New decode: XCD r=id%8 owns bm strip (bm = (id>>3)/bnN*8+r),
//   iterates bn inside -> A-tile working set ~1MB per XCD L2, fetched once.
//   Per-block math identical -> bit-exact vs R11.
// ---------------------------------------------------------------------------

#define N_GRAPHS 256
#define GRU_H 256
#define SCAN_CHUNK 2048   // 256 threads x 8 elements

typedef __attribute__((ext_vector_type(8))) short short8;   // 8 bf16 (4 VGPRs)
typedef __attribute__((ext_vector_type(4))) float floatx4;  // 4 fp32 acc

typedef unsigned short ushort_t;
typedef unsigned int uint_t;

__device__ __forceinline__ float bflo(uint_t u) { return __uint_as_float(u << 16); }
__device__ __forceinline__ float bfhi(uint_t u) { return __uint_as_float(u & 0xffff0000u); }
__device__ __forceinline__ uint_t f2bf(float f) {           // RNE
    uint_t u = __float_as_uint(f);
    return (u + 0x7fffu + ((u >> 16) & 1u)) >> 16;
}
__device__ __forceinline__ uint_t pack2(float a, float b) {
    return f2bf(a) | (f2bf(b) << 16);
}

// ---- CSR build ------------------------------------------------------------

__global__ void k_hist(const int* __restrict__ dst, int* __restrict__ counts, int E) {
    int e = blockIdx.x * blockDim.x + threadIdx.x;
    if (e < E) atomicAdd(&counts[dst[e]], 1);
}

__global__ __launch_bounds__(256) void k_scan1(const int* __restrict__ counts,
                                               int* __restrict__ rowptr,
                                               int* __restrict__ bsums,
                                               float* __restrict__ dinv, int n) {
    int b = blockIdx.x, t = threadIdx.x;
    int base = b * SCAN_CHUNK + t * 8;
    int v[8];
    int s = 0;
#pragma unroll
    for (int j = 0; j < 8; ++j) {
        int i = base + j;
        int c = (i < n) ? counts[i] : 0;
        v[j] = s;            // exclusive within thread
        s += c;
        if (i < n) dinv[i] = rsqrtf((float)(c + 1));  // +1 self loop
    }
    __shared__ int sd[256];
    sd[t] = s;
    __syncthreads();
    for (int off = 1; off < 256; off <<= 1) {
        int tmp = (t >= off) ? sd[t - off] : 0;
        __syncthreads();
        sd[t] += tmp;
        __syncthreads();
    }
    int texcl = sd[t] - s;
    if (t == 255) bsums[b] = sd[255];
#pragma unroll
    for (int j = 0; j < 8; ++j) {
        int i = base + j;
        if (i < n) rowptr[i] = texcl + v[j];
    }
}

// scan3 (scan2 folded): each block derives its own offset from bsums
__global__ __launch_bounds__(256) void k_scan3(int* __restrict__ rowptr,
                                               int* __restrict__ cursor,
                                               const int* __restrict__ bsums,
                                               int n, int nb) {
    int b = blockIdx.x, t = threadIdx.x;
    __shared__ int s_off;
    if (t == 0) {
        int off = 0, tot = 0;
        for (int i = 0; i < nb; ++i) {
            int v = bsums[i];
            if (i < b) off += v;
            tot += v;
        }
        s_off = off;
        if (b == 0) rowptr[n] = tot;
    }
    __syncthreads();
    int off = s_off;
    int base = b * SCAN_CHUNK + t * 8;
#pragma unroll
    for (int j = 0; j < 8; ++j) {
        int i = base + j;
        if (i < n) { int r = rowptr[i] + off; rowptr[i] = r; cursor[i] = r; }
    }
}

// ---- packed independent kernels: fill | prescale | wt_all | split_all -----

__global__ __launch_bounds__(256) void k_pack(
    const int* __restrict__ src, const int* __restrict__ dst,
    int* __restrict__ cursor, int* __restrict__ col, int E,
    const float4* __restrict__ x, const float* __restrict__ dinv,
    uint4* __restrict__ xs, int N,
    const float* __restrict__ w0, const float* __restrict__ w1,
    const float* __restrict__ w2, ushort_t* __restrict__ wt0,
    ushort_t* __restrict__ wt1, ushort_t* __restrict__ wt2,
    const float* __restrict__ wih0, const float* __restrict__ wih1,
    const float* __restrict__ pw,
    ushort_t* __restrict__ sh0, ushort_t* __restrict__ sl0,
    ushort_t* __restrict__ sh1, ushort_t* __restrict__ sl1,
    ushort_t* __restrict__ sh2, ushort_t* __restrict__ sl2,
    int nf, int np, int nw) {
    int b = blockIdx.x, t = threadIdx.x;
    if (b < nf) {
        int e = b * 256 + t;
        if (e < E) {
            int pos = atomicAdd(&cursor[dst[e]], 1);
            col[pos] = src[e];
        }
    } else if (b < nf + np) {
        int idx = (b - nf) * 256 + t;   // chunk of 8 over N*64
        int n = idx >> 3;
        if (n < N) {
            float dn = dinv[n];
            float4 v0 = x[idx * 2], v1 = x[idx * 2 + 1];
            uint4 o;
            o.x = pack2(v0.x * dn, v0.y * dn);
            o.y = pack2(v0.z * dn, v0.w * dn);
            o.z = pack2(v1.x * dn, v1.y * dn);
            o.w = pack2(v1.z * dn, v1.w * dn);
            xs[idx] = o;
        }
    } else if (b < nf + np + nw) {
        int idx = (b - nf - np) * 256 + t;
        if (idx < 8192) {
            int k = idx >> 7, n = idx & 127;
            wt0[(size_t)n * 64 + k] = (ushort_t)f2bf(w0[idx]);
        } else if (idx < 40960) {
            int i = idx - 8192;
            int k = i >> 8, n = i & 255;
            wt1[(size_t)n * 128 + k] = (ushort_t)f2bf(w1[i]);
        } else if (idx < 172032) {
            int i = idx - 40960;
            int k = i >> 9, n = i & 511;
            wt2[(size_t)n * 256 + k] = (ushort_t)f2bf(w2[i]);
        }
    } else {
        int idx = (b - nf - np - nw) * 256 + t;
        const float* s; ushort_t* H; ushort_t* L; int i;
        if (idx < 393216)      { s = wih0; H = sh0; L = sl0; i = idx; }
        else if (idx < 589824) { s = wih1; H = sh1; L = sl1; i = idx - 393216; }
        else if (idx < 720896) { s = pw;   H = sh2; L = sl2; i = idx - 589824; }
        else return;
        float v = s[i];
        uint_t h = f2bf(v);
        H[i] = (ushort_t)h;
        L[i] = (ushort_t)f2bf(v - __uint_as_float(h << 16));
    }
}

// ---- Edge aggregation (gather over CSR), bf16, fp32 accum, 8x unrolled ----

__device__ __forceinline__ void acc8(float& a0, float& a1, float& a2, float& a3,
                                     float& a4, float& a5, float& a6, float& a7,
                                     const uint4& v) {
    a0 += bflo(v.x); a1 += bfhi(v.x); a2 += bflo(v.y); a3 += bfhi(v.y);
    a4 += bflo(v.z); a5 += bfhi(v.z); a6 += bflo(v.w); a7 += bfhi(v.w);
}

__global__ void k_gather_bf16(const uint4* __restrict__ xs, const int* __restrict__ rp,
                              const int* __restrict__ col, const float* __restrict__ dinv,
                              uint4* __restrict__ agg, int N, int shift /*log2(D/8)*/) {
    int idx = blockIdx.x * blockDim.x + threadIdx.x;
    int n = idx >> shift;
    if (n >= N) return;
    int c = idx & ((1 << shift) - 1);
    int C8 = 1 << shift;
    int a = rp[n], b = rp[n + 1];
    uint4 u = xs[(size_t)n * C8 + c];   // self loop (pre-scaled by dinv[n])
    float a0 = bflo(u.x), a1 = bfhi(u.x), a2 = bflo(u.y), a3 = bfhi(u.y);
    float a4 = bflo(u.z), a5 = bfhi(u.z), a6 = bflo(u.w), a7 = bfhi(u.w);
    int k = a;
    for (; k + 8 <= b; k += 8) {
        int ci[8];
#pragma unroll
        for (int j = 0; j < 8; ++j) ci[j] = col[k + j];
        uint4 v[8];
#pragma unroll
        for (int j = 0; j < 8; ++j) v[j] = xs[(size_t)ci[j] * C8 + c];
#pragma unroll
        for (int j = 0; j < 8; ++j)
            acc8(a0, a1, a2, a3, a4, a5, a6, a7, v[j]);
    }
    for (; k + 4 <= b; k += 4) {
        int ci[4];
#pragma unroll
        for (int j = 0; j < 4; ++j) ci[j] = col[k + j];
        uint4 v[4];
#pragma unroll
        for (int j = 0; j < 4; ++j) v[j] = xs[(size_t)ci[j] * C8 + c];
#pragma unroll
        for (int j = 0; j < 4; ++j)
            acc8(a0, a1, a2, a3, a4, a5, a6, a7, v[j]);
    }
    for (; k < b; ++k) {
        uint4 v = xs[(size_t)col[k] * C8 + c];
        acc8(a0, a1, a2, a3, a4, a5, a6, a7, v);
    }
    float dn = dinv[n];
    uint4 o;
    o.x = pack2(a0 * dn, a1 * dn);
    o.y = pack2(a2 * dn, a3 * dn);
    o.z = pack2(a4 * dn, a5 * dn);
    o.w = pack2(a6 * dn, a7 * dn);
    agg[idx] = o;
}

// ---- MFMA bf16 GEMM (GCN layers): C = postproc(A @ Wt^T + bias) -----------
// 64x64 block tile, BK=64, 4 waves 2x2, each wave 32x32 via 2x2 MFMAs.
// 1D grid, XCD-aware decode: r=id%8 (XCD), bm=((id>>3)>>bnShift)*8+r,
// bn=(id>>3)&(bnN-1). Same-XCD blocks share A tiles in that XCD's L2.
// Optional fused gate: gateArr[row] += dot(relu'd row-slice, gate_w-slice).

__global__ __launch_bounds__(256) void k_gemm_mfma(
    const ushort_t* __restrict__ A, const ushort_t* __restrict__ Wt,
    const float* __restrict__ bias, const float* __restrict__ dinv,
    ushort_t* __restrict__ C, int M, int K, int Nout, int scale_out,
    const float* __restrict__ gate_w, float* __restrict__ gateArr,
    int mB, int bnShift) {
    int id = blockIdx.x;
    int xcd = id & 7;
    int k2 = id >> 3;
    int bnI = k2 & ((1 << bnShift) - 1);
    int bmI = (k2 >> bnShift) * 8 + xcd;
    if (bmI >= mB) return;
    int bm = bmI * 64, bn = bnI * 64;

    __shared__ ushort_t As[64 * 72];   // stride 72 bf16 (144B rows, 16B-aligned)
    __shared__ ushort_t Bs[64 * 72];
    int tid = threadIdx.x;
    int wave = tid >> 6, lane = tid & 63;
    int quad = lane >> 4, lr = lane & 15;
    int wm = (wave & 1) * 32, wn = (wave >> 1) * 32;

    floatx4 zero = {0.f, 0.f, 0.f, 0.f};
    floatx4 acc00 = zero, acc01 = zero, acc10 = zero, acc11 = zero;

    int r0 = tid >> 3,         ko0 = (tid & 7) * 8;
    int r1 = (tid + 256) >> 3, ko1 = ((tid + 256) & 7) * 8;

    for (int k0 = 0; k0 < K; k0 += 64) {
        int ar0 = min(bm + r0, M - 1);
        int ar1 = min(bm + r1, M - 1);
        uint4 av0 = *(const uint4*)(A + (size_t)ar0 * K + k0 + ko0);
        uint4 av1 = *(const uint4*)(A + (size_t)ar1 * K + k0 + ko1);
        uint4 bv0 = *(const uint4*)(Wt + (size_t)(bn + r0) * K + k0 + ko0);
        uint4 bv1 = *(const uint4*)(Wt + (size_t)(bn + r1) * K + k0 + ko1);
        __syncthreads();   // prev iter LDS reads done
        *(uint4*)&As[r0 * 72 + ko0] = av0;
        *(uint4*)&As[r1 * 72 + ko1] = av1;
        *(uint4*)&Bs[r0 * 72 + ko0] = bv0;
        *(uint4*)&Bs[r1 * 72 + ko1] = bv1;
        __syncthreads();
#pragma unroll
        for (int ks = 0; ks < 2; ++ks) {
            short8 af0 = *(short8*)&As[(wm + lr) * 72 + ks * 32 + quad * 8];
            short8 af1 = *(short8*)&As[(wm + 16 + lr) * 72 + ks * 32 + quad * 8];
            short8 bf0 = *(short8*)&Bs[(wn + lr) * 72 + ks * 32 + quad * 8];
            short8 bf1 = *(short8*)&Bs[(wn + 16 + lr) * 72 + ks * 32 + quad * 8];
            acc00 = __builtin_amdgcn_mfma_f32_16x16x32_bf16(af0, bf0, acc00, 0, 0, 0);
            acc01 = __builtin_amdgcn_mfma_f32_16x16x32_bf16(af0, bf1, acc01, 0, 0, 0);
            acc10 = __builtin_amdgcn_mfma_f32_16x16x32_bf16(af1, bf0, acc10, 0, 0, 0);
            acc11 = __builtin_amdgcn_mfma_f32_16x16x32_bf16(af1, bf1, acc11, 0, 0, 0);
        }
    }

    // epilogue: C/D layout col=lane&15, row=quad*4+r (m89-verified)
    float gwv[2] = {0.f, 0.f};
    if (gate_w) {
        gwv[0] = gate_w[bn + wn + lr];
        gwv[1] = gate_w[bn + wn + 16 + lr];
    }
    float pg[2][4] = {};
#pragma unroll
    for (int mi = 0; mi < 2; ++mi) {
#pragma unroll
        for (int ni = 0; ni < 2; ++ni) {
            floatx4 acc = (mi == 0) ? (ni == 0 ? acc00 : acc01)
                                    : (ni == 0 ? acc10 : acc11);
            int col = bn + wn + ni * 16 + lr;
            float bcol = bias[col];
#pragma unroll
            for (int r = 0; r < 4; ++r) {
                int row = bm + wm + mi * 16 + quad * 4 + r;
                if (row < M) {
                    float v = acc[r] + bcol;
                    v = fmaxf(v, 0.0f);
                    if (gate_w) pg[mi][r] += v * gwv[ni];
                    if (scale_out) v *= dinv[row];
                    C[(size_t)row * Nout + col] = (ushort_t)f2bf(v);
                }
            }
        }
    }
    if (gate_w) {
#pragma unroll
        for (int mi = 0; mi < 2; ++mi) {
#pragma unroll
            for (int r = 0; r < 4; ++r) {
                float p = pg[mi][r];
                p += __shfl_down(p, 8, 16);
                p += __shfl_down(p, 4, 16);
                p += __shfl_down(p, 2, 16);
                p += __shfl_down(p, 1, 16);
                if (lr == 0) {
                    int row = bm + wm + mi * 16 + quad * 4 + r;
                    if (row < M) atomicAdd(&gateArr[row], p);
                }
            }
        }
    }
}

// ---- split-precision MFMA GEMM (GRU/proj): C_f32 = A @ W^T (+bias) --------

__global__ __launch_bounds__(256) void k_gemm3(
    const ushort_t* __restrict__ Ahi, const ushort_t* __restrict__ Alo,
    const ushort_t* __restrict__ Whi, const ushort_t* __restrict__ Wlo,
    const float* __restrict__ bias, float* __restrict__ C,
    int M, int K, int Nout) {
    __shared__ ushort_t AsH[64 * 72];
    __shared__ ushort_t AsL[64 * 72];
    __shared__ ushort_t BsH[64 * 72];
    __shared__ ushort_t BsL[64 * 72];
    int tid = threadIdx.x;
    int wave = tid >> 6, lane = tid & 63;
    int quad = lane >> 4, lr = lane & 15;
    int wm = (wave & 1) * 32, wn = (wave >> 1) * 32;
    int bm = blockIdx.x * 64, bn = blockIdx.y * 64;

    floatx4 zero = {0.f, 0.f, 0.f, 0.f};
    floatx4 acc00 = zero, acc01 = zero, acc10 = zero, acc11 = zero;

    int r0 = tid >> 3,         ko0 = (tid & 7) * 8;
    int r1 = (tid + 256) >> 3, ko1 = ((tid + 256) & 7) * 8;

    for (int k0 = 0; k0 < K; k0 += 64) {
        int ar0 = min(bm + r0, M - 1);
        int ar1 = min(bm + r1, M - 1);
        size_t a0o = (size_t)ar0 * K + k0 + ko0, a1o = (size_t)ar1 * K + k0 + ko1;
        size_t b0o = (size_t)(bn + r0) * K + k0 + ko0, b1o = (size_t)(bn + r1) * K + k0 + ko1;
        uint4 ah0 = *(const uint4*)(Ahi + a0o), ah1 = *(const uint4*)(Ahi + a1o);
        uint4 al0 = *(const uint4*)(Alo + a0o), al1 = *(const uint4*)(Alo + a1o);
        uint4 bh0 = *(const uint4*)(Whi + b0o), bh1 = *(const uint4*)(Whi + b1o);
        uint4 bl0 = *(const uint4*)(Wlo + b0o), bl1 = *(const uint4*)(Wlo + b1o);
        __syncthreads();
        *(uint4*)&AsH[r0 * 72 + ko0] = ah0; *(uint4*)&AsH[r1 * 72 + ko1] = ah1;
        *(uint4*)&AsL[r0 * 72 + ko0] = al0; *(uint4*)&AsL[r1 * 72 + ko1] = al1;
        *(uint4*)&BsH[r0 * 72 + ko0] = bh0; *(uint4*)&BsH[r1 * 72 + ko1] = bh1;
        *(uint4*)&BsL[r0 * 72 + ko0] = bl0; *(uint4*)&BsL[r1 * 72 + ko1] = bl1;
        __syncthreads();
#pragma unroll
        for (int ks = 0; ks < 2; ++ks) {
            int a0i = (wm + lr) * 72 + ks * 32 + quad * 8;
            int a1i = (wm + 16 + lr) * 72 + ks * 32 + quad * 8;
            int b0i = (wn + lr) * 72 + ks * 32 + quad * 8;
            int b1i = (wn + 16 + lr) * 72 + ks * 32 + quad * 8;
            short8 afh0 = *(short8*)&AsH[a0i], afh1 = *(short8*)&AsH[a1i];
            short8 afl0 = *(short8*)&AsL[a0i], afl1 = *(short8*)&AsL[a1i];
            short8 bfh0 = *(short8*)&BsH[b0i], bfh1 = *(short8*)&BsH[b1i];
            short8 bfl0 = *(short8*)&BsL[b0i], bfl1 = *(short8*)&BsL[b1i];
            acc00 = __builtin_amdgcn_mfma_f32_16x16x32_bf16(afh0, bfh0, acc00, 0, 0, 0);
            acc00 = __builtin_amdgcn_mfma_f32_16x16x32_bf16(afh0, bfl0, acc00, 0, 0, 0);
            acc00 = __builtin_amdgcn_mfma_f32_16x16x32_bf16(afl0, bfh0, acc00, 0, 0, 0);
            acc01 = __builtin_amdgcn_mfma_f32_16x16x32_bf16(afh0, bfh1, acc01, 0, 0, 0);
            acc01 = __builtin_amdgcn_mfma_f32_16x16x32_bf16(afh0, bfl1, acc01, 0, 0, 0);
            acc01 = __builtin_amdgcn_mfma_f32_16x16x32_bf16(afl0, bfh1, acc01, 0, 0, 0);
            acc10 = __builtin_amdgcn_mfma_f32_16x16x32_bf16(afh1, bfh0, acc10, 0, 0, 0);
            acc10 = __builtin_amdgcn_mfma_f32_16x16x32_bf16(afh1, bfl0, acc10, 0, 0, 0);
            acc10 = __builtin_amdgcn_mfma_f32_16x16x32_bf16(afl1, bfh0, acc10, 0, 0, 0);
            acc11 = __builtin_amdgcn_mfma_f32_16x16x32_bf16(afh1, bfh1, acc11, 0, 0, 0);
            acc11 = __builtin_amdgcn_mfma_f32_16x16x32_bf16(afh1, bfl1, acc11, 0, 0, 0);
            acc11 = __builtin_amdgcn_mfma_f32_16x16x32_bf16(afl1, bfh1, acc11, 0, 0, 0);
        }
    }

#pragma unroll
    for (int mi = 0; mi < 2; ++mi) {
#pragma unroll
        for (int ni = 0; ni < 2; ++ni) {
            floatx4 acc = (mi == 0) ? (ni == 0 ? acc00 : acc01)
                                    : (ni == 0 ? acc10 : acc11);
            int col = bn + wn + ni * 16 + lr;
            float bcol = bias ? bias[col] : 0.0f;
#pragma unroll
            for (int r = 0; r < 4; ++r) {
                int row = bm + wm + mi * 16 + quad * 4 + r;
                if (row < M)
                    C[(size_t)row * Nout + col] = acc[r] + bcol;
            }
        }
    }
}

// ---- GRU gate epilogue (h=0: gh = bhh exactly, h' = (1-z)*n) --------------

__global__ void k_gru_ep(const float* __restrict__ gi, const float* __restrict__ bih,
                         const float* __restrict__ bhh,
                         ushort_t* __restrict__ hhi, ushort_t* __restrict__ hlo, int G) {
    int idx = blockIdx.x * blockDim.x + threadIdx.x;
    int g = idx >> 8, j = idx & 255;
    if (g >= G) return;
    const float* row = gi + (size_t)g * 768;
    float ir = row[j]       + bih[j]       + bhh[j];
    float iz = row[j + 256] + bih[j + 256] + bhh[j + 256];
    float in = row[j + 512] + bih[j + 512];
    float r = 1.0f / (1.0f + expf(-ir));
    float z = 1.0f / (1.0f + expf(-iz));
    float nn = tanhf(in + r * bhh[j + 512]);
    float h = (1.0f - z) * nn;
    uint_t hi = f2bf(h);
    hhi[idx] = (ushort_t)hi;
    hlo[idx] = (ushort_t)f2bf(h - __uint_as_float(hi << 16));
}

// ---- segment softmax + weighted sum -> graph emb (bf16 split pair) --------

__global__ __launch_bounds__(256) void k_softmax_emb(
    const uint_t* __restrict__ x /*bf16 pairs*/, const float* __restrict__ gate,
    const int* __restrict__ batch, int N,
    ushort_t* __restrict__ embH, ushort_t* __restrict__ embL) {
    int g = blockIdx.x;
    int s, e;
    {
        int lo = 0, hi = N;
        while (lo < hi) { int mid = (lo + hi) >> 1; if (batch[mid] < g) lo = mid + 1; else hi = mid; }
        s = lo;
        lo = s; hi = N;
        while (lo < hi) { int mid = (lo + hi) >> 1; if (batch[mid] < g + 1) lo = mid + 1; else hi = mid; }
        e = lo;
    }
    __shared__ float red[256];
    __shared__ float sal[256];
    int tid = threadIdx.x;
    float m = -INFINITY;
    for (int i = s + tid; i < e; i += 256) m = fmaxf(m, gate[i]);
    red[tid] = m; __syncthreads();
    for (int off = 128; off > 0; off >>= 1) {
        if (tid < off) red[tid] = fmaxf(red[tid], red[tid + off]);
        __syncthreads();
    }
    m = red[0]; __syncthreads();
    float ssum = 0.f;
    for (int i = s + tid; i < e; i += 256) ssum += expf(gate[i] - m);
    red[tid] = ssum; __syncthreads();
    for (int off = 128; off > 0; off >>= 1) {
        if (tid < off) red[tid] += red[tid + off];
        __syncthreads();
    }
    float denom = red[0];
    float inv = (denom > 0.f) ? 1.0f / denom : 0.0f;
    float acc0 = 0.f, acc1 = 0.f;
    for (int base = s; base < e; base += 256) {
        int i = base + tid;
        __syncthreads();
        sal[tid] = (i < e) ? expf(gate[i] - m) * inv : 0.0f;
        __syncthreads();
        int cnt = min(256, e - base);
        for (int k = 0; k < cnt; ++k) {
            float a = sal[k];
            uint_t u = x[(size_t)(base + k) * 256 + tid];
            acc0 += a * bflo(u);
            acc1 += a * bfhi(u);
        }
    }
    int i0 = g * 512 + tid * 2;
    uint_t h0 = f2bf(acc0);
    uint_t h1 = f2bf(acc1);
    embH[i0]     = (ushort_t)h0;
    embH[i0 + 1] = (ushort_t)h1;
    embL[i0]     = (ushort_t)f2bf(acc0 - __uint_as_float(h0 << 16));
    embL[i0 + 1] = (ushort_t)f2bf(acc1 - __uint_as_float(h1 << 16));
}

// ---------------------------------------------------------------------------

extern "C" void kernel_launch(void* const* d_in, const int* in_sizes, int n_in,
                              void* d_out, int out_size, void* d_ws, size_t ws_size,
                              hipStream_t stream) {
    const float* x       = (const float*)d_in[0];
    const int*   ei      = (const int*)d_in[1];
    const int*   batch   = (const int*)d_in[2];
    const float* w0      = (const float*)d_in[3];
    const float* b0      = (const float*)d_in[4];
    const float* w1      = (const float*)d_in[5];
    const float* b1      = (const float*)d_in[6];
    const float* w2      = (const float*)d_in[7];
    const float* b2      = (const float*)d_in[8];
    const float* gate_w  = (const float*)d_in[9];
    const float* wih0    = (const float*)d_in[11];
    const float* bih0    = (const float*)d_in[13];
    const float* bhh0    = (const float*)d_in[14];
    const float* wih1    = (const float*)d_in[15];
    const float* bih1    = (const float*)d_in[17];
    const float* bhh1    = (const float*)d_in[18];
    const float* pw      = (const float*)d_in[19];
    const float* pb      = (const float*)d_in[20];
    float* out = (float*)d_out;

    const int N = in_sizes[2];        // 50000 nodes
    const int E = in_sizes[1] / 2;    // 800000 edges
    const int G = N_GRAPHS;           // 256 graphs

    char* base = (char*)d_ws;
    size_t off = 0;
    auto alloc = [&](size_t bytes) -> char* {
        char* p = base + off;
        off = (off + bytes + 255) & ~(size_t)255;
        return p;
    };
    ushort_t* bufA  = (ushort_t*)alloc((size_t)N * 512 * 2);  // xs / final x (bf16)
    ushort_t* bufB  = (ushort_t*)alloc((size_t)N * 512 * 2);  // agg (bf16)
    float* dinv     = (float*)alloc((size_t)N * 4);
    // zeroed range: gateArr, counts (single memset)
    float* gateArr  = (float*)alloc((size_t)N * 4);
    int*   counts   = (int*)alloc((size_t)(N + 1) * 4);
    int*   cursor   = (int*)alloc((size_t)(N + 1) * 4);
    int*   rowptr   = (int*)alloc((size_t)(N + 1) * 4);
    int*   bsums    = (int*)alloc((size_t)256 * 4);
    int*   col      = (int*)alloc((size_t)E * 4);
    ushort_t* wt0   = (ushort_t*)alloc((size_t)128 * 64 * 2);
    ushort_t* wt1   = (ushort_t*)alloc((size_t)256 * 128 * 2);
    ushort_t* wt2   = (ushort_t*)alloc((size_t)512 * 256 * 2);
    ushort_t* ih0H  = (ushort_t*)alloc((size_t)768 * 512 * 2);
    ushort_t* ih0L  = (ushort_t*)alloc((size_t)768 * 512 * 2);
    ushort_t* ih1H  = (ushort_t*)alloc((size_t)768 * 256 * 2);
    ushort_t* ih1L  = (ushort_t*)alloc((size_t)768 * 256 * 2);
    ushort_t* pwH   = (ushort_t*)alloc((size_t)512 * 256 * 2);
    ushort_t* pwL   = (ushort_t*)alloc((size_t)512 * 256 * 2);
    ushort_t* embH  = (ushort_t*)alloc((size_t)G * 512 * 2);
    ushort_t* embL  = (ushort_t*)alloc((size_t)G * 512 * 2);
    ushort_t* h1H   = (ushort_t*)alloc((size_t)G * 256 * 2);
    ushort_t* h1L   = (ushort_t*)alloc((size_t)G * 256 * 2);
    ushort_t* h2H   = (ushort_t*)alloc((size_t)G * 256 * 2);
    ushort_t* h2L   = (ushort_t*)alloc((size_t)G * 256 * 2);
    float* gi       = (float*)alloc((size_t)G * 768 * 4);
    (void)ws_size; (void)n_in; (void)out_size;

    const int* src = ei;
    const int* dst = ei + E;

    const int nb = (N + SCAN_CHUNK - 1) / SCAN_CHUNK;   // 25 for N=50000

    // zero gateArr + counts in one shot (adjacent in carve-up)
    size_t zbytes = (size_t)((char*)counts - (char*)gateArr) + (size_t)(N + 1) * 4;
    hipMemsetAsync(gateArr, 0, zbytes, stream);

    // CSR build + dinv
    k_hist<<<(E + 255) / 256, 256, 0, stream>>>(dst, counts, E);
    k_scan1<<<nb, 256, 0, stream>>>(counts, rowptr, bsums, dinv, N);
    k_scan3<<<nb, 256, 0, stream>>>(rowptr, cursor, bsums, N, nb);

    // packed: fill + prescale + wt_all + split_all (all independent)
    int nf = (E + 255) / 256;
    int np = (N * 8 + 255) / 256;
    int nw = (172032 + 255) / 256;
    int ns = (720896 + 255) / 256;
    k_pack<<<nf + np + nw + ns, 256, 0, stream>>>(
        src, dst, cursor, col, E,
        (const float4*)x, dinv, (uint4*)bufA, N,
        w0, w1, w2, wt0, wt1, wt2,
        wih0, wih1, pw, ih0H, ih0L, ih1H, ih1L, pwH, pwL,
        nf, np, nw);

    int mB = (N + 63) / 64;                 // 782
    int mBpad = ((mB + 7) / 8) * 8;         // 784 (XCD-padded)

    // layer 1: gather D=64, GEMM 64->128 (relu * dinv), bnN=2 (shift 1)
    k_gather_bf16<<<(N * 8 + 255) / 256, 256, 0, stream>>>((const uint4*)bufA, rowptr, col, dinv, (uint4*)bufB, N, 3);
    k_gemm_mfma<<<mBpad * 2, 256, 0, stream>>>(bufB, wt0, b0, dinv, bufA, N, 64, 128, 1, nullptr, nullptr, mB, 1);

    // layer 2: gather D=128, GEMM 128->256 (relu * dinv), bnN=4 (shift 2)
    k_gather_bf16<<<(N * 16 + 255) / 256, 256, 0, stream>>>((const uint4*)bufA, rowptr, col, dinv, (uint4*)bufB, N, 4);
    k_gemm_mfma<<<mBpad * 4, 256, 0, stream>>>(bufB, wt1, b1, dinv, bufA, N, 128, 256, 1, nullptr, nullptr, mB, 2);

    // layer 3: gather D=256, GEMM 256->512 (relu; fused gate), bnN=8 (shift 3)
    k_gather_bf16<<<(N * 32 + 255) / 256, 256, 0, stream>>>((const uint4*)bufA, rowptr, col, dinv, (uint4*)bufB, N, 5);
    k_gemm_mfma<<<mBpad * 8, 256, 0, stream>>>(bufB, wt2, b2, dinv, bufA, N, 256, 512, 0, gate_w, gateArr, mB, 3);

    // attention pool (gstart + emb-split folded in; gate_b cancels in softmax)
    k_softmax_emb<<<G, 256, 0, stream>>>((const uint_t*)bufA, gateArr, batch, N, embH, embL);

    // GRU layer 0: gi = emb @ wih0^T  (M=256, K=512, N=768), then gate math
    k_gemm3<<<dim3(G / 64, 12), 256, 0, stream>>>(embH, embL, ih0H, ih0L, nullptr, gi, G, 512, 768);
    k_gru_ep<<<G, 256, 0, stream>>>(gi, bih0, bhh0, h1H, h1L, G);

    // GRU layer 1: gi = h1 @ wih1^T  (M=256, K=256, N=768)
    k_gemm3<<<dim3(G / 64, 12), 256, 0, stream>>>(h1H, h1L, ih1H, ih1L, nullptr, gi, G, 256, 768);
    k_gru_ep<<<G, 256, 0, stream>>>(gi, bih1, bhh1, h2H, h2L, G);

    // projection: out = h2 @ pw^T + pb  (M=256, K=256, N=512)
    k_gemm3<<<dim3(G / 64, 8), 256, 0, stream>>>(h2H, h2L, pwH, pwL, pb, out, G, 256, 512);
}